// Round 1
// baseline (756.864 us; speedup 1.0000x reference)
//
#include <hip/hip_runtime.h>
#include <hip/hip_bf16.h>
#include <stdint.h>

// ---------------- CSR construction ----------------

__global__ __launch_bounds__(256) void k_deg(const int* __restrict__ dst, int E, int* __restrict__ deg, int N){
  int i = blockIdx.x*256 + threadIdx.x;
  if (i < E){
    int d = dst[i];
    if ((unsigned)d < (unsigned)N) atomicAdd(&deg[d], 1);
  }
}

__global__ __launch_bounds__(256) void k_dinv_fill(const int* __restrict__ deg, float* __restrict__ dinv,
                                                   int* __restrict__ fill, int N){
  int i = blockIdx.x*256 + threadIdx.x;
  if (i < N){ dinv[i] = rsqrtf((float)(deg[i] + 1)); fill[i] = 0; }
}

__global__ __launch_bounds__(256) void k_scan_a(const int* __restrict__ deg, int n,
                                                int* __restrict__ excl, int* __restrict__ bsums){
  __shared__ int sh[256];
  int t = threadIdx.x;
  int base = blockIdx.x*1024 + t*4;
  int v0 = (base+0<n)?deg[base+0]:0;
  int v1 = (base+1<n)?deg[base+1]:0;
  int v2 = (base+2<n)?deg[base+2]:0;
  int v3 = (base+3<n)?deg[base+3]:0;
  int s = v0+v1+v2+v3;
  sh[t] = s; __syncthreads();
  for (int off=1; off<256; off<<=1){
    int x = (t>=off)? sh[t-off] : 0;
    __syncthreads(); sh[t] += x; __syncthreads();
  }
  int et = sh[t] - s;
  if (t == 255) bsums[blockIdx.x] = sh[255];
  int run = et;
  if (base+0<n){ excl[base+0] = run; run += v0; }
  if (base+1<n){ excl[base+1] = run; run += v1; }
  if (base+2<n){ excl[base+2] = run; run += v2; }
  if (base+3<n){ excl[base+3] = run; run += v3; }
}

__global__ __launch_bounds__(256) void k_scan_b(const int* __restrict__ bsums, int* __restrict__ bofs, int nb){
  __shared__ int sh[256];
  int t = threadIdx.x;
  int v = (t<nb)? bsums[t] : 0;
  sh[t] = v; __syncthreads();
  for (int off=1; off<256; off<<=1){
    int x = (t>=off)? sh[t-off] : 0;
    __syncthreads(); sh[t] += x; __syncthreads();
  }
  bofs[t] = sh[t] - v;
}

__global__ __launch_bounds__(256) void k_scan_c(int* __restrict__ ofs, const int* __restrict__ bofs, int n, int E){
  int i = blockIdx.x*256 + threadIdx.x;
  if (i < n) ofs[i] += bofs[i>>10];
  if (i == 0) ofs[n] = E;
}

__global__ __launch_bounds__(256) void k_scatter(const int* __restrict__ src, const int* __restrict__ dst, int E,
                                                 const int* __restrict__ ofs, int* __restrict__ fill,
                                                 int* __restrict__ csr, int N){
  int i = blockIdx.x*256 + threadIdx.x;
  if (i < E){
    int d = dst[i];
    int s = src[i];
    if ((unsigned)d < (unsigned)N && (unsigned)s < (unsigned)N){
      int pos = ofs[d] + atomicAdd(&fill[d], 1);
      csr[pos] = s;
    }
  }
}

// ---------------- g = (X @ W) * dinv[row]   (X:[N,128], W:[128,128]) ----------------
// Block = 4 waves. Wave handles 8 rows; lane owns cols (2l, 2l+1).
// Row indices are wave-uniform -> x reads become scalar loads; W tile lives in LDS.

__global__ __launch_bounds__(256, 2) void k_gemm128(const float* __restrict__ X, const float* __restrict__ W,
                                                    const float* __restrict__ dinv, float* __restrict__ G, int N){
  __shared__ float Wl[128*128];
  {
    const float4* W4 = (const float4*)W; float4* L4 = (float4*)Wl;
    #pragma unroll
    for (int i=0;i<16;++i) L4[threadIdx.x + i*256] = W4[threadIdx.x + i*256];
  }
  __syncthreads();
  int wv   = __builtin_amdgcn_readfirstlane((int)(threadIdx.x >> 6));
  int lane = threadIdx.x & 63;
  int row0 = blockIdx.x*32 + wv*8;
  bool ok = (row0 + 8) <= N;
  int rb = ok ? row0 : 0;
  const float* xr = X + (size_t)rb*128;
  float ax[8], ay[8];
  #pragma unroll
  for (int j=0;j<8;++j){ ax[j]=0.f; ay[j]=0.f; }
  #pragma unroll 4
  for (int k=0;k<128;++k){
    float2 w2 = *(const float2*)&Wl[k*128 + 2*lane];
    #pragma unroll
    for (int j=0;j<8;++j){
      float xv = xr[j*128 + k];          // wave-uniform -> s_load
      ax[j] = fmaf(xv, w2.x, ax[j]);
      ay[j] = fmaf(xv, w2.y, ay[j]);
    }
  }
  if (ok){
    #pragma unroll
    for (int j=0;j<8;++j){
      float dv = dinv[rb + j];
      *(float2*)&G[(size_t)(rb+j)*128 + 2*lane] = make_float2(ax[j]*dv, ay[j]*dv);
    }
  }
}

// ---------------- out[d] = relu(dinv[d]*(g[d] + sum g[src]) + b) ----------------
// One wave per node; lane owns cols (2l, 2l+1) -> 512B coalesced row gathers; no atomics.

__global__ __launch_bounds__(256) void k_agg(const float* __restrict__ G, const int* __restrict__ ofs,
                                             const int* __restrict__ csr, const float* __restrict__ dinv,
                                             const float* __restrict__ bias, float* __restrict__ OUT, int N){
  int wv   = __builtin_amdgcn_readfirstlane((int)(threadIdx.x >> 6));
  int lane = threadIdx.x & 63;
  int d = blockIdx.x*4 + wv;
  if (d >= N) return;
  int c = 2*lane;
  float bx = bias[c], by = bias[c+1];
  int e0 = ofs[d], e1 = ofs[d+1];
  float2 g0 = *(const float2*)&G[(size_t)d*128 + c];
  float a0x=g0.x, a0y=g0.y, a1x=0.f,a1y=0.f,a2x=0.f,a2y=0.f,a3x=0.f,a3y=0.f;
  int e = e0;
  for (; e+8 <= e1; e += 8){
    int s0=csr[e],   s1=csr[e+1], s2=csr[e+2], s3=csr[e+3];
    int s4=csr[e+4], s5=csr[e+5], s6=csr[e+6], s7=csr[e+7];
    float2 v0 = *(const float2*)&G[(size_t)s0*128 + c];
    float2 v1 = *(const float2*)&G[(size_t)s1*128 + c];
    float2 v2 = *(const float2*)&G[(size_t)s2*128 + c];
    float2 v3 = *(const float2*)&G[(size_t)s3*128 + c];
    float2 v4 = *(const float2*)&G[(size_t)s4*128 + c];
    float2 v5 = *(const float2*)&G[(size_t)s5*128 + c];
    float2 v6 = *(const float2*)&G[(size_t)s6*128 + c];
    float2 v7 = *(const float2*)&G[(size_t)s7*128 + c];
    a0x+=v0.x; a0y+=v0.y; a1x+=v1.x; a1y+=v1.y;
    a2x+=v2.x; a2y+=v2.y; a3x+=v3.x; a3y+=v3.y;
    a0x+=v4.x; a0y+=v4.y; a1x+=v5.x; a1y+=v5.y;
    a2x+=v6.x; a2y+=v6.y; a3x+=v7.x; a3y+=v7.y;
  }
  for (; e+4 <= e1; e += 4){
    int s0=csr[e], s1=csr[e+1], s2=csr[e+2], s3=csr[e+3];
    float2 v0 = *(const float2*)&G[(size_t)s0*128 + c];
    float2 v1 = *(const float2*)&G[(size_t)s1*128 + c];
    float2 v2 = *(const float2*)&G[(size_t)s2*128 + c];
    float2 v3 = *(const float2*)&G[(size_t)s3*128 + c];
    a0x+=v0.x; a0y+=v0.y; a1x+=v1.x; a1y+=v1.y;
    a2x+=v2.x; a2y+=v2.y; a3x+=v3.x; a3y+=v3.y;
  }
  for (; e < e1; ++e){
    int s = csr[e];
    float2 v = *(const float2*)&G[(size_t)s*128 + c];
    a0x+=v.x; a0y+=v.y;
  }
  float sx = (a0x+a1x)+(a2x+a3x), sy = (a0y+a1y)+(a2y+a3y);
  float dv = dinv[d];
  float rx = fmaxf(fmaf(dv, sx, bx), 0.f);
  float ry = fmaxf(fmaf(dv, sy, by), 0.f);
  *(float2*)&OUT[(size_t)d*128 + c] = make_float2(rx, ry);
}

// ---------------- heads: mean = H@Wm+bm, logstd = H@Ws+bs  (out cols = 32) ----------------

__global__ __launch_bounds__(256, 2) void k_heads(const float* __restrict__ H, const float* __restrict__ Wm,
                                                  const float* __restrict__ bm, const float* __restrict__ Ws,
                                                  const float* __restrict__ bs, float* __restrict__ OUT, int N){
  __shared__ float Wl[128*32];
  for (int i = threadIdx.x; i < 128*16; i += 256){
    int k = i >> 4, cc = i & 15;
    Wl[k*32 + cc]      = Wm[i];
    Wl[k*32 + 16 + cc] = Ws[i];
  }
  __syncthreads();
  int wv   = __builtin_amdgcn_readfirstlane((int)(threadIdx.x >> 6));
  int lane = threadIdx.x & 63;
  int c = lane & 31;
  int row0 = blockIdx.x*64 + wv*16;
  bool ok = (row0 + 16) <= N;
  int rb = ok ? row0 : 0;
  const float* hr = H + (size_t)rb*128;
  float acc[16];
  #pragma unroll
  for (int j=0;j<16;++j) acc[j]=0.f;
  #pragma unroll 4
  for (int k=0;k<128;++k){
    float wc = Wl[k*32 + c];
    #pragma unroll
    for (int j=0;j<16;++j) acc[j] = fmaf(hr[j*128 + k], wc, acc[j]);
  }
  if (ok && lane < 32){
    float bc = (c<16)? bm[c] : bs[c-16];
    #pragma unroll
    for (int j=0;j<16;++j){
      int r = rb + j;
      float v = acc[j] + bc;
      if (c < 16) OUT[(size_t)r*16 + c] = v;
      else        OUT[(size_t)N*16 + (size_t)r*16 + (c-16)] = v;
    }
  }
}

// ---------------- host ----------------

extern "C" void kernel_launch(void* const* d_in, const int* in_sizes, int n_in,
                              void* d_out, int out_size, void* d_ws, size_t ws_size,
                              hipStream_t stream){
  const float* x  = (const float*)d_in[0];
  const int*   ei = (const int*)d_in[1];
  const float* W1 = (const float*)d_in[2];
  const float* b1 = (const float*)d_in[3];
  const float* W2 = (const float*)d_in[4];
  const float* b2 = (const float*)d_in[5];
  const float* Wm = (const float*)d_in[6];
  const float* bm = (const float*)d_in[7];
  const float* Ws = (const float*)d_in[8];
  const float* bs = (const float*)d_in[9];
  float* out = (float*)d_out;

  int N = in_sizes[0] / 128;
  int E = in_sizes[1] / 2;
  const int* src = ei;
  const int* dst = ei + E;

  char* w = (char*)d_ws;
  size_t o = 0;
  auto alloc = [&](size_t bytes)->char*{
    char* p = w + o; o = (o + bytes + 255) & ~(size_t)255; return p;
  };
  float* dinv = (float*)alloc((size_t)N*4);
  int*   deg  = (int*)  alloc((size_t)N*4);
  int*   ofs  = (int*)  alloc((size_t)(N+1)*4);
  int*   fill = (int*)  alloc((size_t)N*4);
  int*   bsum = (int*)  alloc(256*4);
  int*   bofs = (int*)  alloc(256*4);
  int*   csr  = (int*)  alloc((size_t)E*4);
  float* bufA = (float*)alloc((size_t)N*128*4);
  float* bufB = (float*)alloc((size_t)N*128*4);
  (void)ws_size; (void)n_in; (void)out_size;

  hipMemsetAsync(deg, 0, (size_t)N*4, stream);

  int bE = (E + 255)/256;
  int bN = (N + 255)/256;
  int nb = (N + 1023)/1024;

  k_deg      <<<bE, 256, 0, stream>>>(dst, E, deg, N);
  k_dinv_fill<<<bN, 256, 0, stream>>>(deg, dinv, fill, N);
  k_scan_a   <<<nb, 256, 0, stream>>>(deg, N, ofs, bsum);
  k_scan_b   <<<1,  256, 0, stream>>>(bsum, bofs, nb);
  k_scan_c   <<<bN, 256, 0, stream>>>(ofs, bofs, N, E);
  k_scatter  <<<bE, 256, 0, stream>>>(src, dst, E, ofs, fill, csr, N);

  int gGemm = (N + 31)/32;
  int gAgg  = (N + 3)/4;
  int gHead = (N + 63)/64;

  k_gemm128<<<gGemm, 256, 0, stream>>>(x,    W1, dinv, bufA, N);   // g1
  k_agg    <<<gAgg,  256, 0, stream>>>(bufA, ofs, csr, dinv, b1, bufB, N); // h1 = relu(...)
  k_gemm128<<<gGemm, 256, 0, stream>>>(bufB, W2, dinv, bufA, N);   // g2
  k_agg    <<<gAgg,  256, 0, stream>>>(bufA, ofs, csr, dinv, b2, bufB, N); // h2
  k_heads  <<<gHead, 256, 0, stream>>>(bufB, Wm, bm, Ws, bs, out, N);
}

// Round 2
// 623.354 us; speedup vs baseline: 1.2142x; 1.2142x over previous
//
#include <hip/hip_runtime.h>
#include <hip/hip_bf16.h>
#include <stdint.h>

// ---------------- CSR construction (unchanged from R1) ----------------

__global__ __launch_bounds__(256) void k_deg(const int* __restrict__ dst, int E, int* __restrict__ deg, int N){
  int i = blockIdx.x*256 + threadIdx.x;
  if (i < E){
    int d = dst[i];
    if ((unsigned)d < (unsigned)N) atomicAdd(&deg[d], 1);
  }
}

__global__ __launch_bounds__(256) void k_dinv_fill(const int* __restrict__ deg, float* __restrict__ dinv,
                                                   int* __restrict__ fill, int N){
  int i = blockIdx.x*256 + threadIdx.x;
  if (i < N){ dinv[i] = rsqrtf((float)(deg[i] + 1)); fill[i] = 0; }
}

__global__ __launch_bounds__(256) void k_scan_a(const int* __restrict__ deg, int n,
                                                int* __restrict__ excl, int* __restrict__ bsums){
  __shared__ int sh[256];
  int t = threadIdx.x;
  int base = blockIdx.x*1024 + t*4;
  int v0 = (base+0<n)?deg[base+0]:0;
  int v1 = (base+1<n)?deg[base+1]:0;
  int v2 = (base+2<n)?deg[base+2]:0;
  int v3 = (base+3<n)?deg[base+3]:0;
  int s = v0+v1+v2+v3;
  sh[t] = s; __syncthreads();
  for (int off=1; off<256; off<<=1){
    int x = (t>=off)? sh[t-off] : 0;
    __syncthreads(); sh[t] += x; __syncthreads();
  }
  int et = sh[t] - s;
  if (t == 255) bsums[blockIdx.x] = sh[255];
  int run = et;
  if (base+0<n){ excl[base+0] = run; run += v0; }
  if (base+1<n){ excl[base+1] = run; run += v1; }
  if (base+2<n){ excl[base+2] = run; run += v2; }
  if (base+3<n){ excl[base+3] = run; run += v3; }
}

__global__ __launch_bounds__(256) void k_scan_b(const int* __restrict__ bsums, int* __restrict__ bofs, int nb){
  __shared__ int sh[256];
  int t = threadIdx.x;
  int v = (t<nb)? bsums[t] : 0;
  sh[t] = v; __syncthreads();
  for (int off=1; off<256; off<<=1){
    int x = (t>=off)? sh[t-off] : 0;
    __syncthreads(); sh[t] += x; __syncthreads();
  }
  bofs[t] = sh[t] - v;
}

__global__ __launch_bounds__(256) void k_scan_c(int* __restrict__ ofs, const int* __restrict__ bofs, int n, int E){
  int i = blockIdx.x*256 + threadIdx.x;
  if (i < n) ofs[i] += bofs[i>>10];
  if (i == 0) ofs[n] = E;
}

__global__ __launch_bounds__(256) void k_scatter(const int* __restrict__ src, const int* __restrict__ dst, int E,
                                                 const int* __restrict__ ofs, int* __restrict__ fill,
                                                 int* __restrict__ csr, int N){
  int i = blockIdx.x*256 + threadIdx.x;
  if (i < E){
    int d = dst[i];
    int s = src[i];
    if ((unsigned)d < (unsigned)N && (unsigned)s < (unsigned)N){
      int pos = ofs[d] + atomicAdd(&fill[d], 1);
      csr[pos] = s;
    }
  }
}

// ---------------- g = (X @ W) * dinv[row]   (X:[N,128], W:[128,128]) ----------------
// LDS-tiled: block = 256 thr, tile 128 rows x 128 cols, K in two 64-halves.
// Thread microtile 8x8 (ty=tid>>4 rows 8ty.., tx=tid&15 cols 8tx..).
// Per 2-k: 8x ds_read_b64 (X) + 4x ds_read_b128 (W) + 128 fma -> VALU-bound.

__global__ __launch_bounds__(256, 2) void k_gemm128(const float* __restrict__ X, const float* __restrict__ W,
                                                    const float* __restrict__ dinv, float* __restrict__ G, int N){
  __shared__ float Xl[128*64];   // [row][k'] current K-half, 32 KB
  __shared__ float Wl[64*128];   // [k'][col] current K-half, 32 KB
  const int tid = threadIdx.x;
  const int tx = tid & 15;       // col group: cols 8*tx .. 8*tx+7
  const int ty = tid >> 4;       // row group: rows 8*ty .. 8*ty+7
  const int r0 = blockIdx.x * 128;

  float acc[8][8];
  #pragma unroll
  for (int j=0;j<8;++j)
    #pragma unroll
    for (int c=0;c<8;++c) acc[j][c] = 0.f;

  const float2* X2 = (const float2*)X;
  const float4* W4 = (const float4*)W;
  float2* Xl2 = (float2*)Xl;
  float4* Wl4 = (float4*)Wl;

  for (int kh = 0; kh < 2; ++kh){
    if (kh) __syncthreads();
    // stage X half: 128 rows x 32 float2
    #pragma unroll
    for (int i=0;i<16;++i){
      int t = tid + i*256;           // 0..4095
      int r = t >> 5, j = t & 31;
      int rs = r0 + r; if (rs >= N) rs = N - 1;
      Xl2[r*32 + j] = X2[(size_t)rs*64 + kh*32 + j];
    }
    // stage W half: 64 k' x 32 float4
    #pragma unroll
    for (int i=0;i<8;++i){
      int t = tid + i*256;           // 0..2047
      int k = t >> 5, c4 = t & 31;
      Wl4[k*32 + c4] = W4[(size_t)(kh*64 + k)*32 + c4];
    }
    __syncthreads();

    #pragma unroll 4
    for (int k2 = 0; k2 < 32; ++k2){
      float2 xv[8];
      #pragma unroll
      for (int j=0;j<8;++j) xv[j] = Xl2[(8*ty + j)*32 + k2];
      float4 wa0 = Wl4[(2*k2)*32   + 2*tx];
      float4 wa1 = Wl4[(2*k2)*32   + 2*tx + 1];
      float4 wb0 = Wl4[(2*k2+1)*32 + 2*tx];
      float4 wb1 = Wl4[(2*k2+1)*32 + 2*tx + 1];
      #pragma unroll
      for (int j=0;j<8;++j){
        acc[j][0] = fmaf(xv[j].x, wa0.x, acc[j][0]);
        acc[j][1] = fmaf(xv[j].x, wa0.y, acc[j][1]);
        acc[j][2] = fmaf(xv[j].x, wa0.z, acc[j][2]);
        acc[j][3] = fmaf(xv[j].x, wa0.w, acc[j][3]);
        acc[j][4] = fmaf(xv[j].x, wa1.x, acc[j][4]);
        acc[j][5] = fmaf(xv[j].x, wa1.y, acc[j][5]);
        acc[j][6] = fmaf(xv[j].x, wa1.z, acc[j][6]);
        acc[j][7] = fmaf(xv[j].x, wa1.w, acc[j][7]);
        acc[j][0] = fmaf(xv[j].y, wb0.x, acc[j][0]);
        acc[j][1] = fmaf(xv[j].y, wb0.y, acc[j][1]);
        acc[j][2] = fmaf(xv[j].y, wb0.z, acc[j][2]);
        acc[j][3] = fmaf(xv[j].y, wb0.w, acc[j][3]);
        acc[j][4] = fmaf(xv[j].y, wb1.x, acc[j][4]);
        acc[j][5] = fmaf(xv[j].y, wb1.y, acc[j][5]);
        acc[j][6] = fmaf(xv[j].y, wb1.z, acc[j][6]);
        acc[j][7] = fmaf(xv[j].y, wb1.w, acc[j][7]);
      }
    }
  }

  #pragma unroll
  for (int j=0;j<8;++j){
    int row = r0 + 8*ty + j;
    if (row < N){
      float dv = dinv[row];
      float4 o0 = make_float4(acc[j][0]*dv, acc[j][1]*dv, acc[j][2]*dv, acc[j][3]*dv);
      float4 o1 = make_float4(acc[j][4]*dv, acc[j][5]*dv, acc[j][6]*dv, acc[j][7]*dv);
      float4* Gp = (float4*)&G[(size_t)row*128 + 8*tx];
      Gp[0] = o0; Gp[1] = o1;
    }
  }
}

// ---------------- out[d] = relu(dinv[d]*(g[d] + sum g[src]) + b) ----------------
// One wave per node; lane owns cols (2l, 2l+1) -> 512B coalesced row gathers; no atomics.

__global__ __launch_bounds__(256) void k_agg(const float* __restrict__ G, const int* __restrict__ ofs,
                                             const int* __restrict__ csr, const float* __restrict__ dinv,
                                             const float* __restrict__ bias, float* __restrict__ OUT, int N){
  int wv   = __builtin_amdgcn_readfirstlane((int)(threadIdx.x >> 6));
  int lane = threadIdx.x & 63;
  int d = blockIdx.x*4 + wv;
  if (d >= N) return;
  int c = 2*lane;
  float bx = bias[c], by = bias[c+1];
  int e0 = ofs[d], e1 = ofs[d+1];
  float2 g0 = *(const float2*)&G[(size_t)d*128 + c];
  float a0x=g0.x, a0y=g0.y, a1x=0.f,a1y=0.f,a2x=0.f,a2y=0.f,a3x=0.f,a3y=0.f;
  int e = e0;
  for (; e+8 <= e1; e += 8){
    int s0=csr[e],   s1=csr[e+1], s2=csr[e+2], s3=csr[e+3];
    int s4=csr[e+4], s5=csr[e+5], s6=csr[e+6], s7=csr[e+7];
    float2 v0 = *(const float2*)&G[(size_t)s0*128 + c];
    float2 v1 = *(const float2*)&G[(size_t)s1*128 + c];
    float2 v2 = *(const float2*)&G[(size_t)s2*128 + c];
    float2 v3 = *(const float2*)&G[(size_t)s3*128 + c];
    float2 v4 = *(const float2*)&G[(size_t)s4*128 + c];
    float2 v5 = *(const float2*)&G[(size_t)s5*128 + c];
    float2 v6 = *(const float2*)&G[(size_t)s6*128 + c];
    float2 v7 = *(const float2*)&G[(size_t)s7*128 + c];
    a0x+=v0.x; a0y+=v0.y; a1x+=v1.x; a1y+=v1.y;
    a2x+=v2.x; a2y+=v2.y; a3x+=v3.x; a3y+=v3.y;
    a0x+=v4.x; a0y+=v4.y; a1x+=v5.x; a1y+=v5.y;
    a2x+=v6.x; a2y+=v6.y; a3x+=v7.x; a3y+=v7.y;
  }
  for (; e+4 <= e1; e += 4){
    int s0=csr[e], s1=csr[e+1], s2=csr[e+2], s3=csr[e+3];
    float2 v0 = *(const float2*)&G[(size_t)s0*128 + c];
    float2 v1 = *(const float2*)&G[(size_t)s1*128 + c];
    float2 v2 = *(const float2*)&G[(size_t)s2*128 + c];
    float2 v3 = *(const float2*)&G[(size_t)s3*128 + c];
    a0x+=v0.x; a0y+=v0.y; a1x+=v1.x; a1y+=v1.y;
    a2x+=v2.x; a2y+=v2.y; a3x+=v3.x; a3y+=v3.y;
  }
  for (; e < e1; ++e){
    int s = csr[e];
    float2 v = *(const float2*)&G[(size_t)s*128 + c];
    a0x+=v.x; a0y+=v.y;
  }
  float sx = (a0x+a1x)+(a2x+a3x), sy = (a0y+a1y)+(a2y+a3y);
  float dv = dinv[d];
  float rx = fmaxf(fmaf(dv, sx, bx), 0.f);
  float ry = fmaxf(fmaf(dv, sy, by), 0.f);
  *(float2*)&OUT[(size_t)d*128 + c] = make_float2(rx, ry);
}

// ---------------- heads: mean = H@Wm+bm, logstd = H@Ws+bs  (out cols = 16+16) ----------------
// LDS-tiled like k_gemm128: 128-row tile, K in two halves; Hl stride 66 kills bank conflicts.
// Thread: tx=tid&3 (8 cols), ty=tid>>2 (2 rows). Cols 0-15 -> mean, 16-31 -> logstd.

__global__ __launch_bounds__(256, 2) void k_heads(const float* __restrict__ H, const float* __restrict__ Wm,
                                                  const float* __restrict__ bm, const float* __restrict__ Ws,
                                                  const float* __restrict__ bs, float* __restrict__ OUT, int N){
  __shared__ float Hl[128*66];   // [row][k'] padded stride 66
  __shared__ float Wl[128*32];   // [k][col0-15=Wm,16-31=Ws]
  const int tid = threadIdx.x;
  const int tx = tid & 3;        // col group: 8*tx .. 8*tx+7
  const int ty = tid >> 2;       // rows 2*ty, 2*ty+1
  const int r0 = blockIdx.x * 128;

  for (int i = tid; i < 128*16; i += 256){
    int k = i >> 4, cc = i & 15;
    Wl[k*32 + cc]      = Wm[i];
    Wl[k*32 + 16 + cc] = Ws[i];
  }

  float acc[2][8];
  #pragma unroll
  for (int j=0;j<2;++j)
    #pragma unroll
    for (int c=0;c<8;++c) acc[j][c] = 0.f;

  const float2* H2 = (const float2*)H;
  float2* Hl2 = (float2*)Hl;     // row stride 33 float2
  const float4* Wl4 = (const float4*)Wl;

  for (int kh = 0; kh < 2; ++kh){
    if (kh) __syncthreads();
    #pragma unroll
    for (int i=0;i<16;++i){
      int t = tid + i*256;       // 0..4095
      int r = t >> 5, j = t & 31;
      int rs = r0 + r; if (rs >= N) rs = N - 1;
      Hl2[r*33 + j] = H2[(size_t)rs*64 + kh*32 + j];
    }
    __syncthreads();

    #pragma unroll 4
    for (int k2 = 0; k2 < 32; ++k2){
      float2 x0 = Hl2[(2*ty)*33 + k2];
      float2 x1 = Hl2[(2*ty+1)*33 + k2];
      float4 wa0 = Wl4[(kh*64 + 2*k2)*8   + 2*tx];
      float4 wa1 = Wl4[(kh*64 + 2*k2)*8   + 2*tx + 1];
      float4 wb0 = Wl4[(kh*64 + 2*k2+1)*8 + 2*tx];
      float4 wb1 = Wl4[(kh*64 + 2*k2+1)*8 + 2*tx + 1];
      #pragma unroll
      for (int rr=0;rr<2;++rr){
        float xa = rr ? x1.x : x0.x;
        float xb = rr ? x1.y : x0.y;
        acc[rr][0] = fmaf(xa, wa0.x, acc[rr][0]);
        acc[rr][1] = fmaf(xa, wa0.y, acc[rr][1]);
        acc[rr][2] = fmaf(xa, wa0.z, acc[rr][2]);
        acc[rr][3] = fmaf(xa, wa0.w, acc[rr][3]);
        acc[rr][4] = fmaf(xa, wa1.x, acc[rr][4]);
        acc[rr][5] = fmaf(xa, wa1.y, acc[rr][5]);
        acc[rr][6] = fmaf(xa, wa1.z, acc[rr][6]);
        acc[rr][7] = fmaf(xa, wa1.w, acc[rr][7]);
        acc[rr][0] = fmaf(xb, wb0.x, acc[rr][0]);
        acc[rr][1] = fmaf(xb, wb0.y, acc[rr][1]);
        acc[rr][2] = fmaf(xb, wb0.z, acc[rr][2]);
        acc[rr][3] = fmaf(xb, wb0.w, acc[rr][3]);
        acc[rr][4] = fmaf(xb, wb1.x, acc[rr][4]);
        acc[rr][5] = fmaf(xb, wb1.y, acc[rr][5]);
        acc[rr][6] = fmaf(xb, wb1.z, acc[rr][6]);
        acc[rr][7] = fmaf(xb, wb1.w, acc[rr][7]);
      }
    }
  }

  int c0 = 8*tx;
  float bv[8];
  #pragma unroll
  for (int i=0;i<8;++i) bv[i] = (tx < 2) ? bm[c0+i] : bs[c0+i-16];
  #pragma unroll
  for (int rr=0;rr<2;++rr){
    int row = r0 + 2*ty + rr;
    if (row < N){
      float4 o0 = make_float4(acc[rr][0]+bv[0], acc[rr][1]+bv[1], acc[rr][2]+bv[2], acc[rr][3]+bv[3]);
      float4 o1 = make_float4(acc[rr][4]+bv[4], acc[rr][5]+bv[5], acc[rr][6]+bv[6], acc[rr][7]+bv[7]);
      float* base = (tx < 2) ? &OUT[(size_t)row*16 + c0]
                             : &OUT[(size_t)N*16 + (size_t)row*16 + (c0-16)];
      float4* Op = (float4*)base;
      Op[0] = o0; Op[1] = o1;
    }
  }
}

// ---------------- host ----------------

extern "C" void kernel_launch(void* const* d_in, const int* in_sizes, int n_in,
                              void* d_out, int out_size, void* d_ws, size_t ws_size,
                              hipStream_t stream){
  const float* x  = (const float*)d_in[0];
  const int*   ei = (const int*)d_in[1];
  const float* W1 = (const float*)d_in[2];
  const float* b1 = (const float*)d_in[3];
  const float* W2 = (const float*)d_in[4];
  const float* b2 = (const float*)d_in[5];
  const float* Wm = (const float*)d_in[6];
  const float* bm = (const float*)d_in[7];
  const float* Ws = (const float*)d_in[8];
  const float* bs = (const float*)d_in[9];
  float* out = (float*)d_out;

  int N = in_sizes[0] / 128;
  int E = in_sizes[1] / 2;
  const int* src = ei;
  const int* dst = ei + E;

  char* w = (char*)d_ws;
  size_t o = 0;
  auto alloc = [&](size_t bytes)->char*{
    char* p = w + o; o = (o + bytes + 255) & ~(size_t)255; return p;
  };
  float* dinv = (float*)alloc((size_t)N*4);
  int*   deg  = (int*)  alloc((size_t)N*4);
  int*   ofs  = (int*)  alloc((size_t)(N+1)*4);
  int*   fill = (int*)  alloc((size_t)N*4);
  int*   bsum = (int*)  alloc(256*4);
  int*   bofs = (int*)  alloc(256*4);
  int*   csr  = (int*)  alloc((size_t)E*4);
  float* bufA = (float*)alloc((size_t)N*128*4);
  float* bufB = (float*)alloc((size_t)N*128*4);
  (void)ws_size; (void)n_in; (void)out_size;

  hipMemsetAsync(deg, 0, (size_t)N*4, stream);

  int bE = (E + 255)/256;
  int bN = (N + 255)/256;
  int nb = (N + 1023)/1024;

  k_deg      <<<bE, 256, 0, stream>>>(dst, E, deg, N);
  k_dinv_fill<<<bN, 256, 0, stream>>>(deg, dinv, fill, N);
  k_scan_a   <<<nb, 256, 0, stream>>>(deg, N, ofs, bsum);
  k_scan_b   <<<1,  256, 0, stream>>>(bsum, bofs, nb);
  k_scan_c   <<<bN, 256, 0, stream>>>(ofs, bofs, N, E);
  k_scatter  <<<bE, 256, 0, stream>>>(src, dst, E, ofs, fill, csr, N);

  int gTile = (N + 127)/128;
  int gAgg  = (N + 3)/4;

  k_gemm128<<<gTile, 256, 0, stream>>>(x,    W1, dinv, bufA, N);   // g1
  k_agg    <<<gAgg,  256, 0, stream>>>(bufA, ofs, csr, dinv, b1, bufB, N); // h1 = relu(...)
  k_gemm128<<<gTile, 256, 0, stream>>>(bufB, W2, dinv, bufA, N);   // g2
  k_agg    <<<gAgg,  256, 0, stream>>>(bufA, ofs, csr, dinv, b2, bufB, N); // h2
  k_heads  <<<gTile, 256, 0, stream>>>(bufB, Wm, bm, Ws, bs, out, N);
}

// Round 5
// 558.620 us; speedup vs baseline: 1.3549x; 1.1159x over previous
//
#include <hip/hip_runtime.h>
#include <hip/hip_bf16.h>
#include <stdint.h>

static __device__ __forceinline__ ushort f2bf(float f){
  uint u = __float_as_uint(f);
  uint r = (u + 0x7fffu + ((u >> 16) & 1u)) >> 16;   // round-to-nearest-even
  return (ushort)r;
}

// ---------------- CSR construction ----------------

__global__ __launch_bounds__(256) void k_deg(const int* __restrict__ dst, int E, int* __restrict__ deg){
  int i = blockIdx.x*256 + threadIdx.x;
  int base = i*4;
  if (base + 4 <= E){
    int4 d4 = *(const int4*)&dst[base];
    atomicAdd(&deg[d4.x], 1);
    atomicAdd(&deg[d4.y], 1);
    atomicAdd(&deg[d4.z], 1);
    atomicAdd(&deg[d4.w], 1);
  } else {
    for (int j = base; j < E; ++j) atomicAdd(&deg[dst[j]], 1);
  }
}

__global__ __launch_bounds__(256) void k_dinv_fill(const int* __restrict__ deg, float* __restrict__ dinv, int N){
  int i = blockIdx.x*256 + threadIdx.x;
  if (i < N) dinv[i] = rsqrtf((float)(deg[i] + 1));
}

__global__ __launch_bounds__(256) void k_scan_a(const int* __restrict__ deg, int n,
                                                int* __restrict__ excl, int* __restrict__ bsums){
  __shared__ int sh[256];
  int t = threadIdx.x;
  int base = blockIdx.x*1024 + t*4;
  int v0 = (base+0<n)?deg[base+0]:0;
  int v1 = (base+1<n)?deg[base+1]:0;
  int v2 = (base+2<n)?deg[base+2]:0;
  int v3 = (base+3<n)?deg[base+3]:0;
  int s = v0+v1+v2+v3;
  sh[t] = s; __syncthreads();
  for (int off=1; off<256; off<<=1){
    int x = (t>=off)? sh[t-off] : 0;
    __syncthreads(); sh[t] += x; __syncthreads();
  }
  int et = sh[t] - s;
  if (t == 255) bsums[blockIdx.x] = sh[255];
  int run = et;
  if (base+0<n){ excl[base+0] = run; run += v0; }
  if (base+1<n){ excl[base+1] = run; run += v1; }
  if (base+2<n){ excl[base+2] = run; run += v2; }
  if (base+3<n){ excl[base+3] = run; run += v3; }
}

__global__ __launch_bounds__(256) void k_scan_b(const int* __restrict__ bsums, int* __restrict__ bofs, int nb){
  __shared__ int sh[256];
  int t = threadIdx.x;
  int v = (t<nb)? bsums[t] : 0;
  sh[t] = v; __syncthreads();
  for (int off=1; off<256; off<<=1){
    int x = (t>=off)? sh[t-off] : 0;
    __syncthreads(); sh[t] += x; __syncthreads();
  }
  bofs[t] = sh[t] - v;
}

__global__ __launch_bounds__(256) void k_scan_c(int* __restrict__ ofs, const int* __restrict__ bofs,
                                                int* __restrict__ cursor, int n, int E){
  int i = blockIdx.x*256 + threadIdx.x;
  if (i < n){
    int v = ofs[i] + bofs[i>>10];
    ofs[i] = v;
    cursor[i] = v;
  }
  if (i == 0) ofs[n] = E;
}

__global__ __launch_bounds__(256) void k_scatter(const int* __restrict__ src, const int* __restrict__ dst, int E,
                                                 int* __restrict__ cursor, int* __restrict__ csr){
  int i = blockIdx.x*256 + threadIdx.x;
  int base = i*4;
  if (base + 4 <= E){
    int4 d4 = *(const int4*)&dst[base];
    int4 s4 = *(const int4*)&src[base];
    int p0 = atomicAdd(&cursor[d4.x], 1); csr[p0] = s4.x;
    int p1 = atomicAdd(&cursor[d4.y], 1); csr[p1] = s4.y;
    int p2 = atomicAdd(&cursor[d4.z], 1); csr[p2] = s4.z;
    int p3 = atomicAdd(&cursor[d4.w], 1); csr[p3] = s4.w;
  } else {
    for (int j = base; j < E; ++j){
      int p = atomicAdd(&cursor[dst[j]], 1); csr[p] = src[j];
    }
  }
}

// ---------------- g = bf16((X @ W) * dinv[row])   (X:[N,128] fp32, W:[128,128]) ----------------

__global__ __launch_bounds__(256, 2) void k_gemm128(const float* __restrict__ X, const float* __restrict__ W,
                                                    const float* __restrict__ dinv, ushort* __restrict__ G, int N){
  __shared__ float Xl[128*64];   // [row][k'] current K-half, 32 KB
  __shared__ float Wl[64*128];   // [k'][col] current K-half, 32 KB
  const int tid = threadIdx.x;
  const int tx = tid & 15;       // col group: cols 8*tx .. 8*tx+7
  const int ty = tid >> 4;       // row group: rows 8*ty .. 8*ty+7
  const int r0 = blockIdx.x * 128;

  float acc[8][8];
  #pragma unroll
  for (int j=0;j<8;++j)
    #pragma unroll
    for (int c=0;c<8;++c) acc[j][c] = 0.f;

  const float2* X2 = (const float2*)X;
  const float4* W4 = (const float4*)W;
  float2* Xl2 = (float2*)Xl;
  float4* Wl4 = (float4*)Wl;

  for (int kh = 0; kh < 2; ++kh){
    if (kh) __syncthreads();
    #pragma unroll
    for (int i=0;i<16;++i){
      int t = tid + i*256;           // 0..4095
      int r = t >> 5, j = t & 31;
      int rs = r0 + r; if (rs >= N) rs = N - 1;
      Xl2[r*32 + j] = X2[(size_t)rs*64 + kh*32 + j];
    }
    #pragma unroll
    for (int i=0;i<8;++i){
      int t = tid + i*256;           // 0..2047
      int k = t >> 5, c4 = t & 31;
      Wl4[k*32 + c4] = W4[(size_t)(kh*64 + k)*32 + c4];
    }
    __syncthreads();

    #pragma unroll 4
    for (int k2 = 0; k2 < 32; ++k2){
      float2 xv[8];
      #pragma unroll
      for (int j=0;j<8;++j) xv[j] = Xl2[(8*ty + j)*32 + k2];
      float4 wa0 = Wl4[(2*k2)*32   + 2*tx];
      float4 wa1 = Wl4[(2*k2)*32   + 2*tx + 1];
      float4 wb0 = Wl4[(2*k2+1)*32 + 2*tx];
      float4 wb1 = Wl4[(2*k2+1)*32 + 2*tx + 1];
      #pragma unroll
      for (int j=0;j<8;++j){
        acc[j][0] = fmaf(xv[j].x, wa0.x, acc[j][0]);
        acc[j][1] = fmaf(xv[j].x, wa0.y, acc[j][1]);
        acc[j][2] = fmaf(xv[j].x, wa0.z, acc[j][2]);
        acc[j][3] = fmaf(xv[j].x, wa0.w, acc[j][3]);
        acc[j][4] = fmaf(xv[j].x, wa1.x, acc[j][4]);
        acc[j][5] = fmaf(xv[j].x, wa1.y, acc[j][5]);
        acc[j][6] = fmaf(xv[j].x, wa1.z, acc[j][6]);
        acc[j][7] = fmaf(xv[j].x, wa1.w, acc[j][7]);
        acc[j][0] = fmaf(xv[j].y, wb0.x, acc[j][0]);
        acc[j][1] = fmaf(xv[j].y, wb0.y, acc[j][1]);
        acc[j][2] = fmaf(xv[j].y, wb0.z, acc[j][2]);
        acc[j][3] = fmaf(xv[j].y, wb0.w, acc[j][3]);
        acc[j][4] = fmaf(xv[j].y, wb1.x, acc[j][4]);
        acc[j][5] = fmaf(xv[j].y, wb1.y, acc[j][5]);
        acc[j][6] = fmaf(xv[j].y, wb1.z, acc[j][6]);
        acc[j][7] = fmaf(xv[j].y, wb1.w, acc[j][7]);
      }
    }
  }

  #pragma unroll
  for (int j=0;j<8;++j){
    int row = r0 + 8*ty + j;
    if (row < N){
      float dv = dinv[row];
      uint p0 = (uint)f2bf(acc[j][0]*dv) | ((uint)f2bf(acc[j][1]*dv) << 16);
      uint p1 = (uint)f2bf(acc[j][2]*dv) | ((uint)f2bf(acc[j][3]*dv) << 16);
      uint p2 = (uint)f2bf(acc[j][4]*dv) | ((uint)f2bf(acc[j][5]*dv) << 16);
      uint p3 = (uint)f2bf(acc[j][6]*dv) | ((uint)f2bf(acc[j][7]*dv) << 16);
      uint4* Gp = (uint4*)&G[(size_t)row*128 + 8*tx];
      *Gp = make_uint4(p0, p1, p2, p3);
    }
  }
}

// ---------------- out[d] = relu(dinv[d]*(g[d] + sum g[src]) + b)  (G bf16, OUT fp32) ----------------
// One wave per node; lane owns cols (2l, 2l+1) = one u32 of 2 bf16 -> 256B coalesced row gathers.

__global__ __launch_bounds__(256) void k_agg(const ushort* __restrict__ G, const int* __restrict__ ofs,
                                             const int* __restrict__ csr, const float* __restrict__ dinv,
                                             const float* __restrict__ bias, float* __restrict__ OUT, int N){
  int wv   = __builtin_amdgcn_readfirstlane((int)(threadIdx.x >> 6));
  int lane = threadIdx.x & 63;
  int d = blockIdx.x*4 + wv;
  if (d >= N) return;
  const uint* Gu = (const uint*)G;    // row stride 64 uints
  float bx = bias[2*lane], by = bias[2*lane+1];
  int e0 = ofs[d], e1 = ofs[d+1];
  uint u0 = Gu[(size_t)d*64 + lane];
  float a0x = __uint_as_float(u0 << 16), a0y = __uint_as_float(u0 & 0xffff0000u);
  float a1x=0.f,a1y=0.f,a2x=0.f,a2y=0.f,a3x=0.f,a3y=0.f;
  int e = e0;
  for (; e+8 <= e1; e += 8){
    int s0=csr[e],   s1=csr[e+1], s2=csr[e+2], s3=csr[e+3];
    int s4=csr[e+4], s5=csr[e+5], s6=csr[e+6], s7=csr[e+7];
    uint v0 = Gu[(size_t)s0*64 + lane];
    uint v1 = Gu[(size_t)s1*64 + lane];
    uint v2 = Gu[(size_t)s2*64 + lane];
    uint v3 = Gu[(size_t)s3*64 + lane];
    uint v4 = Gu[(size_t)s4*64 + lane];
    uint v5 = Gu[(size_t)s5*64 + lane];
    uint v6 = Gu[(size_t)s6*64 + lane];
    uint v7 = Gu[(size_t)s7*64 + lane];
    a0x += __uint_as_float(v0 << 16); a0y += __uint_as_float(v0 & 0xffff0000u);
    a1x += __uint_as_float(v1 << 16); a1y += __uint_as_float(v1 & 0xffff0000u);
    a2x += __uint_as_float(v2 << 16); a2y += __uint_as_float(v2 & 0xffff0000u);
    a3x += __uint_as_float(v3 << 16); a3y += __uint_as_float(v3 & 0xffff0000u);
    a0x += __uint_as_float(v4 << 16); a0y += __uint_as_float(v4 & 0xffff0000u);
    a1x += __uint_as_float(v5 << 16); a1y += __uint_as_float(v5 & 0xffff0000u);
    a2x += __uint_as_float(v6 << 16); a2y += __uint_as_float(v6 & 0xffff0000u);
    a3x += __uint_as_float(v7 << 16); a3y += __uint_as_float(v7 & 0xffff0000u);
  }
  for (; e+4 <= e1; e += 4){
    int s0=csr[e], s1=csr[e+1], s2=csr[e+2], s3=csr[e+3];
    uint v0 = Gu[(size_t)s0*64 + lane];
    uint v1 = Gu[(size_t)s1*64 + lane];
    uint v2 = Gu[(size_t)s2*64 + lane];
    uint v3 = Gu[(size_t)s3*64 + lane];
    a0x += __uint_as_float(v0 << 16); a0y += __uint_as_float(v0 & 0xffff0000u);
    a1x += __uint_as_float(v1 << 16); a1y += __uint_as_float(v1 & 0xffff0000u);
    a2x += __uint_as_float(v2 << 16); a2y += __uint_as_float(v2 & 0xffff0000u);
    a3x += __uint_as_float(v3 << 16); a3y += __uint_as_float(v3 & 0xffff0000u);
  }
  for (; e < e1; ++e){
    int s = csr[e];
    uint v = Gu[(size_t)s*64 + lane];
    a0x += __uint_as_float(v << 16); a0y += __uint_as_float(v & 0xffff0000u);
  }
  float sx = (a0x+a1x)+(a2x+a3x), sy = (a0y+a1y)+(a2y+a3y);
  float dv = dinv[d];
  float rx = fmaxf(fmaf(dv, sx, bx), 0.f);
  float ry = fmaxf(fmaf(dv, sy, by), 0.f);
  *(float2*)&OUT[(size_t)d*128 + 2*lane] = make_float2(rx, ry);
}

// ---------------- heads: mean = H@Wm+bm, logstd = H@Ws+bs  (H fp32, out cols = 16+16) ----------------

__global__ __launch_bounds__(256, 2) void k_heads(const float* __restrict__ H, const float* __restrict__ Wm,
                                                  const float* __restrict__ bm, const float* __restrict__ Ws,
                                                  const float* __restrict__ bs, float* __restrict__ OUT, int N){
  __shared__ float Hl[128*66];   // [row][k'] padded stride 66
  __shared__ float Wl[128*32];   // [k][col0-15=Wm,16-31=Ws]
  const int tid = threadIdx.x;
  const int tx = tid & 3;        // col group: 8*tx .. 8*tx+7
  const int ty = tid >> 2;       // rows 2*ty, 2*ty+1
  const int r0 = blockIdx.x * 128;

  for (int i = tid; i < 128*16; i += 256){
    int k = i >> 4, cc = i & 15;
    Wl[k*32 + cc]      = Wm[i];
    Wl[k*32 + 16 + cc] = Ws[i];
  }

  float acc[2][8];
  #pragma unroll
  for (int j=0;j<2;++j)
    #pragma unroll
    for (int c=0;c<8;++c) acc[j][c] = 0.f;

  const float2* H2 = (const float2*)H;
  float2* Hl2 = (float2*)Hl;     // row stride 33 float2
  const float4* Wl4 = (const float4*)Wl;

  for (int kh = 0; kh < 2; ++kh){
    if (kh) __syncthreads();
    #pragma unroll
    for (int i=0;i<16;++i){
      int t = tid + i*256;       // 0..4095
      int r = t >> 5, j = t & 31;
      int rs = r0 + r; if (rs >= N) rs = N - 1;
      Hl2[r*33 + j] = H2[(size_t)rs*64 + kh*32 + j];
    }
    __syncthreads();

    #pragma unroll 4
    for (int k2 = 0; k2 < 32; ++k2){
      float2 x0 = Hl2[(2*ty)*33 + k2];
      float2 x1 = Hl2[(2*ty+1)*33 + k2];
      float4 wa0 = Wl4[(kh*64 + 2*k2)*8   + 2*tx];
      float4 wa1 = Wl4[(kh*64 + 2*k2)*8   + 2*tx + 1];
      float4 wb0 = Wl4[(kh*64 + 2*k2+1)*8 + 2*tx];
      float4 wb1 = Wl4[(kh*64 + 2*k2+1)*8 + 2*tx + 1];
      #pragma unroll
      for (int rr=0;rr<2;++rr){
        float xa = rr ? x1.x : x0.x;
        float xb = rr ? x1.y : x0.y;
        acc[rr][0] = fmaf(xa, wa0.x, acc[rr][0]);
        acc[rr][1] = fmaf(xa, wa0.y, acc[rr][1]);
        acc[rr][2] = fmaf(xa, wa0.z, acc[rr][2]);
        acc[rr][3] = fmaf(xa, wa0.w, acc[rr][3]);
        acc[rr][4] = fmaf(xa, wa1.x, acc[rr][4]);
        acc[rr][5] = fmaf(xa, wa1.y, acc[rr][5]);
        acc[rr][6] = fmaf(xa, wa1.z, acc[rr][6]);
        acc[rr][7] = fmaf(xa, wa1.w, acc[rr][7]);
        acc[rr][0] = fmaf(xb, wb0.x, acc[rr][0]);
        acc[rr][1] = fmaf(xb, wb0.y, acc[rr][1]);
        acc[rr][2] = fmaf(xb, wb0.z, acc[rr][2]);
        acc[rr][3] = fmaf(xb, wb0.w, acc[rr][3]);
        acc[rr][4] = fmaf(xb, wb1.x, acc[rr][4]);
        acc[rr][5] = fmaf(xb, wb1.y, acc[rr][5]);
        acc[rr][6] = fmaf(xb, wb1.z, acc[rr][6]);
        acc[rr][7] = fmaf(xb, wb1.w, acc[rr][7]);
      }
    }
  }

  int c0 = 8*tx;
  float bv[8];
  #pragma unroll
  for (int i=0;i<8;++i) bv[i] = (tx < 2) ? bm[c0+i] : bs[c0+i-16];
  #pragma unroll
  for (int rr=0;rr<2;++rr){
    int row = r0 + 2*ty + rr;
    if (row < N){
      float4 o0 = make_float4(acc[rr][0]+bv[0], acc[rr][1]+bv[1], acc[rr][2]+bv[2], acc[rr][3]+bv[3]);
      float4 o1 = make_float4(acc[rr][4]+bv[4], acc[rr][5]+bv[5], acc[rr][6]+bv[6], acc[rr][7]+bv[7]);
      float* base = (tx < 2) ? &OUT[(size_t)row*16 + c0]
                             : &OUT[(size_t)N*16 + (size_t)row*16 + (c0-16)];
      float4* Op = (float4*)base;
      Op[0] = o0; Op[1] = o1;
    }
  }
}

// ---------------- host ----------------

extern "C" void kernel_launch(void* const* d_in, const int* in_sizes, int n_in,
                              void* d_out, int out_size, void* d_ws, size_t ws_size,
                              hipStream_t stream){
  const float* x  = (const float*)d_in[0];
  const int*   ei = (const int*)d_in[1];
  const float* W1 = (const float*)d_in[2];
  const float* b1 = (const float*)d_in[3];
  const float* W2 = (const float*)d_in[4];
  const float* b2 = (const float*)d_in[5];
  const float* Wm = (const float*)d_in[6];
  const float* bm = (const float*)d_in[7];
  const float* Ws = (const float*)d_in[8];
  const float* bs = (const float*)d_in[9];
  float* out = (float*)d_out;

  int N = in_sizes[0] / 128;
  int E = in_sizes[1] / 2;
  const int* src = ei;
  const int* dst = ei + E;

  char* w = (char*)d_ws;
  size_t o = 0;
  auto alloc = [&](size_t bytes)->char*{
    char* p = w + o; o = (o + bytes + 255) & ~(size_t)255; return p;
  };
  float*  dinv   = (float*) alloc((size_t)N*4);
  int*    deg    = (int*)   alloc((size_t)N*4);
  int*    ofs    = (int*)   alloc((size_t)(N+1)*4);
  int*    cursor = (int*)   alloc((size_t)N*4);
  int*    bsum   = (int*)   alloc(256*4);
  int*    bofs   = (int*)   alloc(256*4);
  int*    csr    = (int*)   alloc((size_t)E*4);
  ushort* bufG   = (ushort*)alloc((size_t)N*128*2);   // bf16 G (both layers)
  float*  bufH   = (float*) alloc((size_t)N*128*4);   // fp32 h (both layers)
  (void)ws_size; (void)n_in; (void)out_size;

  hipMemsetAsync(deg, 0, (size_t)N*4, stream);

  int bE4 = (E/4 + 255)/256;
  int bN  = (N + 255)/256;
  int nb  = (N + 1023)/1024;

  k_deg      <<<bE4, 256, 0, stream>>>(dst, E, deg);
  k_dinv_fill<<<bN,  256, 0, stream>>>(deg, dinv, N);
  k_scan_a   <<<nb,  256, 0, stream>>>(deg, N, ofs, bsum);
  k_scan_b   <<<1,   256, 0, stream>>>(bsum, bofs, nb);
  k_scan_c   <<<bN,  256, 0, stream>>>(ofs, bofs, cursor, N, E);
  k_scatter  <<<bE4, 256, 0, stream>>>(src, dst, E, cursor, csr);

  int gTile = (N + 127)/128;
  int gAgg  = (N + 3)/4;

  k_gemm128<<<gTile, 256, 0, stream>>>(x,    W1, dinv, bufG, N);             // g1 (bf16)
  k_agg    <<<gAgg,  256, 0, stream>>>(bufG, ofs, csr, dinv, b1, bufH, N);   // h1 = relu(...) fp32
  k_gemm128<<<gTile, 256, 0, stream>>>(bufH, W2, dinv, bufG, N);             // g2 (bf16)
  k_agg    <<<gAgg,  256, 0, stream>>>(bufG, ofs, csr, dinv, b2, bufH, N);   // h2 fp32
  k_heads  <<<gTile, 256, 0, stream>>>(bufH, Wm, bm, Ws, bs, out, N);
}